// Round 3
// baseline (1214.788 us; speedup 1.0000x reference)
//
#include <hip/hip_runtime.h>
#include <hip/hip_bf16.h>

#define NN 50000
#define NE 800000
#define DIMX 288
#define NPB 16   // nodes per block in k_linear1 / k_gate

typedef float float4v __attribute__((ext_vector_type(4)));
typedef short short8 __attribute__((ext_vector_type(8)));

__device__ __forceinline__ float b2f(unsigned short u) {
  return __uint_as_float(((unsigned int)u) << 16);
}
__device__ __forceinline__ unsigned short f2b(float f) {
  unsigned int x = __float_as_uint(f);
  x += 0x7fffu + ((x >> 16) & 1u);
  return (unsigned short)(x >> 16);
}
__device__ __forceinline__ float ldf(const void* p, long i, int f32) {
  return f32 ? ((const float*)p)[i] : b2f(((const unsigned short*)p)[i]);
}
__device__ __forceinline__ int ldidx(const int* p, long i, int i64) {
  return i64 ? p[2 * i] : p[i];
}

// ---------------- Kernel 0: dtype detector ----------------
__global__ void k_detect(const unsigned short* __restrict__ pos_u16,
                         const int* __restrict__ eidx_i32,
                         int* __restrict__ flags) {
  if (threadIdx.x == 0 && blockIdx.x == 0) {
    int insane = 0;
    for (int i = 0; i < 128; ++i) {
      unsigned short u = pos_u16[i];
      int e = (u >> 7) & 0xff;
      if (e >= 0xC2) insane++;          // |x| >= 2^67 impossible for bf16 pos in [0,10]
    }
    flags[0] = (insane >= 2) ? 1 : 0;
    int nz = 0;
    for (int i = 1; i < 16; i += 2) nz += (eidx_i32[i] != 0);
    flags[1] = (nz == 0) ? 1 : 0;       // int64 high words all zero
  }
}

// ---------------- Counting sort by dst: zero-cnt, hist, scan, scatter ----------------
__global__ __launch_bounds__(256) void k_zero_cnt(int* __restrict__ cnt) {
  int i = blockIdx.x * 256 + threadIdx.x;
  if (i < NN) cnt[i] = 0;
}

__global__ __launch_bounds__(256) void k_hist(const int* __restrict__ eidx,
                                              int* __restrict__ cnt,
                                              const int* __restrict__ flags) {
  const int i64 = flags[1];
  long e = (long)blockIdx.x * 256 + threadIdx.x;
  if (e < NE) {
    int d = ldidx(eidx, NE + e, i64);
    atomicAdd(&cnt[d], 1);
  }
}

// single block, 1024 threads: exclusive prefix sum of cnt -> cursor
__global__ __launch_bounds__(1024) void k_scan(const int* __restrict__ cnt,
                                               int* __restrict__ cursor) {
  __shared__ int part[1024];
  int t = threadIdx.x;
  const int CH = (NN + 1023) / 1024;   // 49
  int lo = t * CH, hi = lo + CH; if (hi > NN) hi = NN;
  int s = 0;
  for (int i = lo; i < hi; ++i) s += cnt[i];
  part[t] = s;
  __syncthreads();
  for (int off = 1; off < 1024; off <<= 1) {
    int v = (t >= off) ? part[t - off] : 0;
    __syncthreads();
    part[t] += v;
    __syncthreads();
  }
  int run = (t > 0) ? part[t - 1] : 0;
  for (int i = lo; i < hi; ++i) { int c = cnt[i]; cursor[i] = run; run += c; }
}

__global__ __launch_bounds__(256) void k_scatter(const int* __restrict__ eidx,
                                                 int* __restrict__ cursor,
                                                 unsigned long long* __restrict__ sedge,
                                                 const int* __restrict__ flags) {
  const int i64 = flags[1];
  long e = (long)blockIdx.x * 256 + threadIdx.x;
  if (e < NE) {
    int s = ldidx(eidx, e, i64);
    int d = ldidx(eidx, NE + e, i64);
    int p = atomicAdd(&cursor[d], 1);
    sedge[p] = ((unsigned long long)(unsigned)d << 32) | (unsigned)s;
  }
}

// ---------------- Kernel 1: si1 = irreps_linear(nodes) -> bf16 ----------------
__global__ __launch_bounds__(256) void k_linear1(
    const void* __restrict__ nodes,
    const void* __restrict__ W0,
    const void* __restrict__ W1,
    const void* __restrict__ W2,
    unsigned short* __restrict__ si1,
    const int* __restrict__ flags) {
  const int f32 = flags[0];
  __shared__ float Ws[3072];
  __shared__ float xs[NPB * DIMX];
  int tid = threadIdx.x;
  for (int idx = tid; idx < 3072; idx += 256) {
    int l = idx >> 10, rem = idx & 1023;
    const void* w = (l == 0) ? W0 : ((l == 1) ? W1 : W2);
    Ws[idx] = ldf(w, rem, f32);
  }
  long base = (long)blockIdx.x * NPB;
  for (int idx = tid; idx < NPB * DIMX; idx += 256)
    xs[idx] = ldf(nodes, base * DIMX + idx, f32);
  __syncthreads();
  int wid = tid >> 6, lane = tid & 63;
  #pragma unroll 1
  for (int t = 0; t < 4; ++t) {
    int nl = wid * 4 + t;
    long node = base + nl;
    const float* x = xs + nl * DIMX;
    #pragma unroll
    for (int r = 0; r < 5; ++r) {
      int j = r * 64 + lane;
      if (j < DIMX) {
        float acc = 0.f;
        if (j < 32) {
          #pragma unroll
          for (int i = 0; i < 32; ++i) acc += x[i] * Ws[i * 32 + j];
        } else if (j < 128) {
          unsigned jj = j - 32; int m = jj / 3u, c = jj % 3u;
          #pragma unroll
          for (int i = 0; i < 32; ++i) acc += x[32 + 3 * i + c] * Ws[1024 + i * 32 + m];
        } else {
          unsigned jj = j - 128; int m = jj / 5u, c = jj % 5u;
          #pragma unroll
          for (int i = 0; i < 32; ++i) acc += x[128 + 5 * i + c] * Ws[2048 + i * 32 + m];
        }
        si1[node * DIMX + j] = f2b(acc);
      }
    }
  }
}

// ---------------- Kernel 2: zero the conv accumulator ----------------
__global__ __launch_bounds__(256) void k_zero(float* __restrict__ conv) {
  long idx = (long)blockIdx.x * 256 + threadIdx.x;
  if (idx < (long)NN * DIMX / 4) {
    float4 z; z.x = 0.f; z.y = 0.f; z.z = 0.f; z.w = 0.f;
    ((float4*)conv)[idx] = z;
  }
}

// ---------------- Kernel 3: fused edge kernel (dst-sorted edges) ----------------
// LDS-pipe-bound fix round: wall writes b128 (transposed [j][4] layout),
// h-build reads b128, geomY reads b128, per-lane X[j] values read directly
// from global (u16 coalesced, VMEM pipe) instead of LDS. LDS row cache kept
// only for cross-reads (l1/l2 dot inputs + X[m]).
__global__ __launch_bounds__(256) void k_edges(
    const void* __restrict__ pos,
    const unsigned long long* __restrict__ sedge,
    const void* __restrict__ Wr1,
    const void* __restrict__ br1,
    const void* __restrict__ Wr2,
    const unsigned short* __restrict__ si1,
    float* __restrict__ conv,
    const int* __restrict__ flags) {
  const int f32 = flags[0];
  // bufA: phase A = wr2t[j*72+k] (16128 shorts); phase B = row cache [64][288]
  __shared__ __align__(16) unsigned short bufA[18432];
  // bufB: phase A = wr1s[512]+br1[64] @0, rbf[64][8] @576; phase B = wall[4][228*4]
  __shared__ __align__(16) float bufB[3648];
  __shared__ __align__(16) float geomY[64][8];  // Y1(3) Y2(5), live whole kernel
  __shared__ unsigned int sdv[2][64];           // src, dst
  int tid = threadIdx.x, lane = tid & 63, wid = tid >> 6;

  for (int idx = tid; idx < 512; idx += 256) bufB[idx] = ldf(Wr1, idx, f32);
  if (tid < 64) bufB[512 + tid] = ldf(br1, tid, f32);
  for (int idx = tid; idx < 64 * 224; idx += 256) {   // global-coalesced, transpose into LDS
    int k = idx / 224, j = idx - k * 224;
    bufA[j * 72 + k] = f2b(ldf(Wr2, idx, f32));
  }
  if (tid < 64) {
    long e = (long)blockIdx.x * 64 + tid;
    unsigned long long pr = sedge[e];
    int s = (int)(pr & 0xffffffffu);
    int d = (int)(pr >> 32);
    sdv[0][tid] = (unsigned)s; sdv[1][tid] = (unsigned)d;
    float rx = ldf(pos, 3 * (long)s, f32)     - ldf(pos, 3 * (long)d, f32);
    float ry = ldf(pos, 3 * (long)s + 1, f32) - ldf(pos, 3 * (long)d + 1, f32);
    float rz = ldf(pos, 3 * (long)s + 2, f32) - ldf(pos, 3 * (long)d + 2, f32);
    float dd = sqrtf(rx * rx + ry * ry + rz * rz + 1e-12f);
    float inv = 1.0f / dd;
    float ux = rx * inv, uy = ry * inv, uz = rz * inv;
    geomY[tid][0] = ux; geomY[tid][1] = uy; geomY[tid][2] = uz;
    geomY[tid][3] = ux * uy;
    geomY[tid][4] = uy * uz;
    geomY[tid][5] = (3.f * uz * uz - 1.f) * 0.28867513459481287f;
    geomY[tid][6] = ux * uz;
    geomY[tid][7] = (ux * ux - uy * uy) * 0.5f;
    #pragma unroll
    for (int k = 0; k < 8; ++k) {
      float t = dd - (float)k * (5.0f / 7.0f);
      bufB[576 + tid * 8 + k] = __expf(-t * t);   // rbf
    }
  }
  __syncthreads();

  const int q = lane >> 4, colA = lane & 15;
  const int myrow0 = wid * 16;

  // --- h (scaled by 0.25 = 1/sqrt(AVG_DEG)) into A-fragments (b128 LDS reads) ---
  short8 afrag0, afrag1;
  {
    const float* rb = &bufB[576 + (myrow0 + colA) * 8];
    float rbv[8];
    #pragma unroll
    for (int r = 0; r < 8; ++r) rbv[r] = rb[r];
    float a0[8], a1[8];
    {
      float4v b0 = *(const float4v*)&bufB[512 + q * 8];
      float4v b1 = *(const float4v*)&bufB[512 + q * 8 + 4];
      float4v b2 = *(const float4v*)&bufB[512 + 32 + q * 8];
      float4v b3 = *(const float4v*)&bufB[512 + 32 + q * 8 + 4];
      #pragma unroll
      for (int i = 0; i < 4; ++i) {
        a0[i] = b0[i]; a0[4 + i] = b1[i];
        a1[i] = b2[i]; a1[4 + i] = b3[i];
      }
    }
    #pragma unroll
    for (int r = 0; r < 8; ++r) {
      float4v wA = *(const float4v*)&bufB[r * 64 + q * 8];
      float4v wB = *(const float4v*)&bufB[r * 64 + q * 8 + 4];
      float4v wC = *(const float4v*)&bufB[r * 64 + 32 + q * 8];
      float4v wD = *(const float4v*)&bufB[r * 64 + 32 + q * 8 + 4];
      float rv = rbv[r];
      #pragma unroll
      for (int i = 0; i < 4; ++i) {
        a0[i]     += rv * wA[i];
        a0[4 + i] += rv * wB[i];
        a1[i]     += rv * wC[i];
        a1[4 + i] += rv * wD[i];
      }
    }
    #pragma unroll
    for (int i = 0; i < 8; ++i) {
      float a = a0[i];
      afrag0[i] = (short)f2b(0.25f * a / (1.f + __expf(-a)));
      float a2 = a1[i];
      afrag1[i] = (short)f2b(0.25f * a2 / (1.f + __expf(-a2)));
    }
  }

  // --- 28 MFMA: w for all 16 edges of this wave ---
  float4v acc[14];
  #pragma unroll
  for (int t = 0; t < 14; ++t) {
    int j = t * 16 + colA;
    short8 b0 = *(const short8*)&bufA[j * 72 + q * 8];
    short8 b1 = *(const short8*)&bufA[j * 72 + 32 + q * 8];
    float4v c = {0.f, 0.f, 0.f, 0.f};
    c = __builtin_amdgcn_mfma_f32_16x16x32_bf16(afrag0, b0, c, 0, 0, 0);
    c = __builtin_amdgcn_mfma_f32_16x16x32_bf16(afrag1, b1, c, 0, 0, 0);
    acc[t] = c;
  }

  __syncthreads();   // wr2t + wr1s/rbf dead; bufA -> row cache, bufB -> wall

  // --- batch-gather this wave's 16 source rows (bf16, raw copy, b128 I/O) ---
  if (lane < 36) {
    #pragma unroll
    for (int b = 0; b < 2; ++b) {
      uint4 t[8];
      #pragma unroll
      for (int e = 0; e < 8; ++e) {
        unsigned s = sdv[0][myrow0 + b * 8 + e];
        t[e] = ((const uint4*)(si1 + (size_t)s * DIMX))[lane];
      }
      #pragma unroll
      for (int e = 0; e < 8; ++e) {
        ((uint4*)&bufA[(size_t)(myrow0 + b * 8 + e) * 288])[lane] = t[e];
      }
    }
  }

  // --- per-lane output accumulators for the current dst run ---
  float accv[5] = {0.f, 0.f, 0.f, 0.f, 0.f};
  unsigned cur_d = sdv[1][myrow0];
  float* wallw = bufB + wid * 912;      // transposed wall: wallw[j*4 + edge]

  #pragma unroll 1
  for (int g = 0; g < 4; ++g) {
    // unload w for this 4-edge group: one b128 store per t (14 instrs)
    asm volatile("" ::: "memory");
    if (q == g) {
      #pragma unroll
      for (int t = 0; t < 14; ++t)
        *(float4v*)&wallw[(t * 16 + colA) * 4] = acc[t];
    }
    asm volatile("" ::: "memory");

    #pragma unroll
    for (int reg = 0; reg < 4; ++reg) {
      const int eb = myrow0 + g * 4 + reg;
      // per-lane diagonal X values: direct global u16 (VMEM pipe, coalesced)
      const unsigned short* Xrow = si1 + (size_t)sdv[0][eb] * DIMX;
      float xj[5];
      #pragma unroll
      for (int r = 0; r < 5; ++r) {
        int j = r * 64 + lane;
        xj[r] = (j < DIMX) ? b2f(Xrow[j]) : 0.f;
      }
      float4v g0 = *(const float4v*)&geomY[eb][0];
      float4v g1 = *(const float4v*)&geomY[eb][4];
      float y1x = g0[0], y1y = g0[1], y1z = g0[2], y20 = g0[3];
      float y21 = g1[0], y22 = g1[1], y23 = g1[2], y24 = g1[3];
      const unsigned short* X = &bufA[(size_t)eb * 288];
      #define WV(c) wallw[(c) * 4 + reg]
      float v[5];
      #pragma unroll
      for (int r = 0; r < 5; ++r) {
        int j = r * 64 + lane;
        if (j < DIMX) {
          if (j < 32) {
            int m = j;
            float d1 = b2f(X[32 + 3 * m]) * y1x + b2f(X[33 + 3 * m]) * y1y + b2f(X[34 + 3 * m]) * y1z;
            float d2 = b2f(X[128 + 5 * m]) * y20 + b2f(X[129 + 5 * m]) * y21 + b2f(X[130 + 5 * m]) * y22
                     + b2f(X[131 + 5 * m]) * y23 + b2f(X[132 + 5 * m]) * y24;
            v[r] = WV(m) * xj[r] + WV(128 + m) * d1 + WV(192 + m) * d2;
          } else if (j < 128) {
            unsigned jj = j - 32; int m = jj / 3u, c = jj % 3u;
            float Yc = (c == 0) ? y1x : ((c == 1) ? y1y : y1z);
            v[r] = WV(32 + m) * xj[r] + WV(96 + m) * b2f(X[m]) * Yc;
          } else {
            unsigned jj = j - 128; int m = jj / 5u, c = jj % 5u;
            float Yc = (c == 0) ? y20 : (c == 1) ? y21 : (c == 2) ? y22 : (c == 3) ? y23 : y24;
            v[r] = WV(64 + m) * xj[r] + WV(160 + m) * b2f(X[m]) * Yc;
          }
        }
      }
      #undef WV
      // serial run-accumulate / flush
      unsigned dn = sdv[1][eb];
      if (dn != cur_d) {               // wave-uniform: flush the finished run
        float* cv = conv + (size_t)cur_d * DIMX;
        #pragma unroll
        for (int r = 0; r < 5; ++r) {
          int j = r * 64 + lane;
          if (j < DIMX) { atomicAdd(cv + j, accv[r]); accv[r] = 0.f; }
        }
        cur_d = dn;
      }
      #pragma unroll
      for (int r = 0; r < 5; ++r) {
        int j = r * 64 + lane;
        if (j < DIMX) accv[r] += v[r];
      }
    }
    asm volatile("" ::: "memory");
  }
  // final flush for the last run
  {
    float* cv = conv + (size_t)cur_d * DIMX;
    #pragma unroll
    for (int r = 0; r < 5; ++r) {
      int j = r * 64 + lane;
      if (j < DIMX) atomicAdd(cv + j, accv[r]);
    }
  }
}

// ---------------- Kernel 4: si2 = linear(conv); mixed = nodes + si2; gate -> fp32 ----------------
__global__ __launch_bounds__(256) void k_gate(
    const float* __restrict__ conv,
    const void* __restrict__ nodes,
    const void* __restrict__ W0,
    const void* __restrict__ W1,
    const void* __restrict__ W2,
    const void* __restrict__ Wg,
    float* __restrict__ out,
    const int* __restrict__ flags) {
  const int f32 = flags[0];
  __shared__ float Ws[3072];
  __shared__ float Wgs[2048];
  __shared__ float xs[NPB * DIMX];
  __shared__ float m0s[NPB][33];
  __shared__ float gs[NPB][65];
  int tid = threadIdx.x;
  for (int idx = tid; idx < 3072; idx += 256) {
    int l = idx >> 10, rem = idx & 1023;
    const void* w = (l == 0) ? W0 : ((l == 1) ? W1 : W2);
    Ws[idx] = ldf(w, rem, f32);
  }
  for (int idx = tid; idx < 2048; idx += 256) Wgs[idx] = ldf(Wg, idx, f32);
  long base = (long)blockIdx.x * NPB;
  for (int idx = tid; idx < NPB * DIMX; idx += 256) xs[idx] = conv[base * DIMX + idx];
  __syncthreads();
  int wid = tid >> 6, lane = tid & 63;
  #pragma unroll 1
  for (int t = 0; t < 4; ++t) {
    int nl = wid * 4 + t;
    long node = base + nl;
    const float* x = xs + nl * DIMX;
    float mixed[5];
    #pragma unroll
    for (int r = 0; r < 5; ++r) {
      int j = r * 64 + lane;
      if (j < DIMX) {
        float acc = 0.f;
        if (j < 32) {
          #pragma unroll
          for (int i = 0; i < 32; ++i) acc += x[i] * Ws[i * 32 + j];
        } else if (j < 128) {
          unsigned jj = j - 32; int m = jj / 3u, c = jj % 3u;
          #pragma unroll
          for (int i = 0; i < 32; ++i) acc += x[32 + 3 * i + c] * Ws[1024 + i * 32 + m];
        } else {
          unsigned jj = j - 128; int m = jj / 5u, c = jj % 5u;
          #pragma unroll
          for (int i = 0; i < 32; ++i) acc += x[128 + 5 * i + c] * Ws[2048 + i * 32 + m];
        }
        acc += ldf(nodes, node * DIMX + j, f32);
        mixed[r] = acc;
        if (j < 32) m0s[nl][j] = acc;
      }
    }
    asm volatile("" ::: "memory");
    {
      float ga = 0.f;
      #pragma unroll
      for (int m = 0; m < 32; ++m) ga += m0s[nl][m] * Wgs[m * 64 + lane];
      gs[nl][lane] = 1.f / (1.f + __expf(-ga));
    }
    asm volatile("" ::: "memory");
    #pragma unroll
    for (int r = 0; r < 5; ++r) {
      int j = r * 64 + lane;
      if (j < DIMX) {
        float v = mixed[r];
        float o;
        if (j < 32) {
          o = v / (1.f + __expf(-v));
        } else if (j < 128) {
          int m = (unsigned)(j - 32) / 3u; o = v * gs[nl][m];
        } else {
          int m = (unsigned)(j - 128) / 5u; o = v * gs[nl][32 + m];
        }
        out[node * DIMX + j] = o;
      }
    }
  }
}

extern "C" void kernel_launch(void* const* d_in, const int* in_sizes, int n_in,
                              void* d_out, int out_size, void* d_ws, size_t ws_size,
                              hipStream_t stream) {
  const void* nodes = d_in[0];
  const void* pos   = d_in[1];
  const void* W0    = d_in[2];
  const void* W1    = d_in[3];
  const void* W2    = d_in[4];
  const void* Wr1   = d_in[5];
  const void* br1   = d_in[6];
  const void* Wr2   = d_in[7];
  const void* Wg    = d_in[8];
  const int* eidx   = (const int*)d_in[10];

  // workspace layout
  int* flags = (int*)d_ws;
  unsigned short* si1 = (unsigned short*)((char*)d_ws + 256);
  size_t conv_off = 256 + (size_t)NN * DIMX * 2;                 // 28,800,256
  float* conv = (float*)((char*)d_ws + conv_off);
  size_t cnt_off = conv_off + (size_t)NN * DIMX * 4;             // 86,400,256
  int* cnt    = (int*)((char*)d_ws + cnt_off);
  int* cursor = (int*)((char*)d_ws + cnt_off + (size_t)NN * 4);  // 86,600,256
  unsigned long long* sedge =
      (unsigned long long*)((char*)d_ws + cnt_off + 2 * (size_t)NN * 4);  // 86,800,256
  float* out = (float*)d_out;

  hipLaunchKernelGGL(k_detect, dim3(1), dim3(64), 0, stream,
                     (const unsigned short*)pos, eidx, flags);
  // counting sort of edges by dst
  hipLaunchKernelGGL(k_zero_cnt, dim3((NN + 255) / 256), dim3(256), 0, stream, cnt);
  hipLaunchKernelGGL(k_hist, dim3((NE + 255) / 256), dim3(256), 0, stream, eidx, cnt, flags);
  hipLaunchKernelGGL(k_scan, dim3(1), dim3(1024), 0, stream, cnt, cursor);
  hipLaunchKernelGGL(k_scatter, dim3((NE + 255) / 256), dim3(256), 0, stream,
                     eidx, cursor, sedge, flags);
  // node pipeline
  hipLaunchKernelGGL(k_linear1, dim3(NN / NPB), dim3(256), 0, stream,
                     nodes, W0, W1, W2, si1, flags);
  hipLaunchKernelGGL(k_zero, dim3((NN * DIMX / 4 + 255) / 256), dim3(256), 0, stream, conv);
  hipLaunchKernelGGL(k_edges, dim3(NE / 64), dim3(256), 0, stream,
                     pos, sedge, Wr1, br1, Wr2, si1, conv, flags);
  hipLaunchKernelGGL(k_gate, dim3(NN / NPB), dim3(256), 0, stream,
                     conv, nodes, W0, W1, W2, Wg, out, flags);
}

// Round 4
// 1206.133 us; speedup vs baseline: 1.0072x; 1.0072x over previous
//
#include <hip/hip_runtime.h>
#include <hip/hip_bf16.h>

#define NN 50000
#define NE 800000
#define DIMX 288
#define NPB 16   // nodes per block in k_linear1 / k_gate

typedef float float4v __attribute__((ext_vector_type(4)));
typedef short short8 __attribute__((ext_vector_type(8)));

__device__ __forceinline__ float b2f(unsigned short u) {
  return __uint_as_float(((unsigned int)u) << 16);
}
__device__ __forceinline__ unsigned short f2b(float f) {
  unsigned int x = __float_as_uint(f);
  x += 0x7fffu + ((x >> 16) & 1u);
  return (unsigned short)(x >> 16);
}
__device__ __forceinline__ float ldf(const void* p, long i, int f32) {
  return f32 ? ((const float*)p)[i] : b2f(((const unsigned short*)p)[i]);
}
__device__ __forceinline__ int ldidx(const int* p, long i, int i64) {
  return i64 ? p[2 * i] : p[i];
}

// ---------------- Kernel 0: dtype detector ----------------
__global__ void k_detect(const unsigned short* __restrict__ pos_u16,
                         const int* __restrict__ eidx_i32,
                         int* __restrict__ flags) {
  if (threadIdx.x == 0 && blockIdx.x == 0) {
    int insane = 0;
    for (int i = 0; i < 128; ++i) {
      unsigned short u = pos_u16[i];
      int e = (u >> 7) & 0xff;
      if (e >= 0xC2) insane++;          // |x| >= 2^67 impossible for bf16 pos in [0,10]
    }
    flags[0] = (insane >= 2) ? 1 : 0;
    int nz = 0;
    for (int i = 1; i < 16; i += 2) nz += (eidx_i32[i] != 0);
    flags[1] = (nz == 0) ? 1 : 0;       // int64 high words all zero
  }
}

// ---------------- Counting sort by dst: zero-cnt, hist, scan, scatter ----------------
__global__ __launch_bounds__(256) void k_zero_cnt(int* __restrict__ cnt) {
  int i = blockIdx.x * 256 + threadIdx.x;
  if (i < NN) cnt[i] = 0;
}

__global__ __launch_bounds__(256) void k_hist(const int* __restrict__ eidx,
                                              int* __restrict__ cnt,
                                              const int* __restrict__ flags) {
  const int i64 = flags[1];
  long e = (long)blockIdx.x * 256 + threadIdx.x;
  if (e < NE) {
    int d = ldidx(eidx, NE + e, i64);
    atomicAdd(&cnt[d], 1);
  }
}

// single block, 1024 threads: exclusive prefix sum of cnt -> cursor
__global__ __launch_bounds__(1024) void k_scan(const int* __restrict__ cnt,
                                               int* __restrict__ cursor) {
  __shared__ int part[1024];
  int t = threadIdx.x;
  const int CH = (NN + 1023) / 1024;   // 49
  int lo = t * CH, hi = lo + CH; if (hi > NN) hi = NN;
  int s = 0;
  for (int i = lo; i < hi; ++i) s += cnt[i];
  part[t] = s;
  __syncthreads();
  for (int off = 1; off < 1024; off <<= 1) {
    int v = (t >= off) ? part[t - off] : 0;
    __syncthreads();
    part[t] += v;
    __syncthreads();
  }
  int run = (t > 0) ? part[t - 1] : 0;
  for (int i = lo; i < hi; ++i) { int c = cnt[i]; cursor[i] = run; run += c; }
}

__global__ __launch_bounds__(256) void k_scatter(const int* __restrict__ eidx,
                                                 int* __restrict__ cursor,
                                                 unsigned long long* __restrict__ sedge,
                                                 const int* __restrict__ flags) {
  const int i64 = flags[1];
  long e = (long)blockIdx.x * 256 + threadIdx.x;
  if (e < NE) {
    int s = ldidx(eidx, e, i64);
    int d = ldidx(eidx, NE + e, i64);
    int p = atomicAdd(&cursor[d], 1);
    sedge[p] = ((unsigned long long)(unsigned)d << 32) | (unsigned)s;
  }
}

// ---------------- Kernel 1: si1 = irreps_linear(nodes) -> bf16 ----------------
__global__ __launch_bounds__(256) void k_linear1(
    const void* __restrict__ nodes,
    const void* __restrict__ W0,
    const void* __restrict__ W1,
    const void* __restrict__ W2,
    unsigned short* __restrict__ si1,
    const int* __restrict__ flags) {
  const int f32 = flags[0];
  __shared__ float Ws[3072];
  __shared__ float xs[NPB * DIMX];
  int tid = threadIdx.x;
  for (int idx = tid; idx < 3072; idx += 256) {
    int l = idx >> 10, rem = idx & 1023;
    const void* w = (l == 0) ? W0 : ((l == 1) ? W1 : W2);
    Ws[idx] = ldf(w, rem, f32);
  }
  long base = (long)blockIdx.x * NPB;
  for (int idx = tid; idx < NPB * DIMX; idx += 256)
    xs[idx] = ldf(nodes, base * DIMX + idx, f32);
  __syncthreads();
  int wid = tid >> 6, lane = tid & 63;
  #pragma unroll 1
  for (int t = 0; t < 4; ++t) {
    int nl = wid * 4 + t;
    long node = base + nl;
    const float* x = xs + nl * DIMX;
    #pragma unroll
    for (int r = 0; r < 5; ++r) {
      int j = r * 64 + lane;
      if (j < DIMX) {
        float acc = 0.f;
        if (j < 32) {
          #pragma unroll
          for (int i = 0; i < 32; ++i) acc += x[i] * Ws[i * 32 + j];
        } else if (j < 128) {
          unsigned jj = j - 32; int m = jj / 3u, c = jj % 3u;
          #pragma unroll
          for (int i = 0; i < 32; ++i) acc += x[32 + 3 * i + c] * Ws[1024 + i * 32 + m];
        } else {
          unsigned jj = j - 128; int m = jj / 5u, c = jj % 5u;
          #pragma unroll
          for (int i = 0; i < 32; ++i) acc += x[128 + 5 * i + c] * Ws[2048 + i * 32 + m];
        }
        si1[node * DIMX + j] = f2b(acc);
      }
    }
  }
}

// ---------------- Kernel 2: zero the conv accumulator ----------------
__global__ __launch_bounds__(256) void k_zero(float* __restrict__ conv) {
  long idx = (long)blockIdx.x * 256 + threadIdx.x;
  if (idx < (long)NN * DIMX / 4) {
    float4 z; z.x = 0.f; z.y = 0.f; z.z = 0.f; z.w = 0.f;
    ((float4*)conv)[idx] = z;
  }
}

// ---------------- Kernel 3: fused edge kernel (dst-sorted edges) ----------------
// Restructured phase B: lane<->m mapping. lane m (=lane&31) owns multiplicity m;
// half-wave h (=lane>>5) owns edges myrow0+8h..+8h+7 (contiguous: dst runs
// preserved per half). Per edge, lane m computes all 9 outputs
// {m0[m], m1[m][0..2], m2[m][0..4]} from 9 direct global u16 reads of the src
// row (prefetched one edge ahead; VMEM pipe was idle), 7 LDS u16 w-reads, and
// 2 b128 Y reads. No LDS row cache, no gather, no divergent branches; w is
// unloaded ONCE per wave as bf16 into wall[224][18] (stride-9-word: conflict-
// free). LDS ~39KB -> 4 blocks/CU.
__global__ __launch_bounds__(256) void k_edges(
    const void* __restrict__ pos,
    const unsigned long long* __restrict__ sedge,
    const void* __restrict__ Wr1,
    const void* __restrict__ br1,
    const void* __restrict__ Wr2,
    const unsigned short* __restrict__ si1,
    float* __restrict__ conv,
    const int* __restrict__ flags) {
  const int f32 = flags[0];
  // bufA: phase A = wr2t[j*72+k] (16128 shorts); phase B = wall[4 waves][224][18] bf16
  __shared__ __align__(16) unsigned short bufA[16128];
  // bufB: phase A only = wr1s[512]+br1[64] @0, rbf[64][8] @576
  __shared__ __align__(16) float bufB[1088];
  __shared__ __align__(16) float geomY[64][8];  // Y1(3) Y2(5), live whole kernel
  __shared__ unsigned int sdv[2][64];           // src, dst
  int tid = threadIdx.x, lane = tid & 63, wid = tid >> 6;

  for (int idx = tid; idx < 512; idx += 256) bufB[idx] = ldf(Wr1, idx, f32);
  if (tid < 64) bufB[512 + tid] = ldf(br1, tid, f32);
  for (int idx = tid; idx < 64 * 224; idx += 256) {   // global-coalesced, transpose into LDS
    int k = idx / 224, j = idx - k * 224;
    bufA[j * 72 + k] = f2b(ldf(Wr2, idx, f32));
  }
  if (tid < 64) {
    long e = (long)blockIdx.x * 64 + tid;
    unsigned long long pr = sedge[e];
    int s = (int)(pr & 0xffffffffu);
    int d = (int)(pr >> 32);
    sdv[0][tid] = (unsigned)s; sdv[1][tid] = (unsigned)d;
    float rx = ldf(pos, 3 * (long)s, f32)     - ldf(pos, 3 * (long)d, f32);
    float ry = ldf(pos, 3 * (long)s + 1, f32) - ldf(pos, 3 * (long)d + 1, f32);
    float rz = ldf(pos, 3 * (long)s + 2, f32) - ldf(pos, 3 * (long)d + 2, f32);
    float dd = sqrtf(rx * rx + ry * ry + rz * rz + 1e-12f);
    float inv = 1.0f / dd;
    float ux = rx * inv, uy = ry * inv, uz = rz * inv;
    geomY[tid][0] = ux; geomY[tid][1] = uy; geomY[tid][2] = uz;
    geomY[tid][3] = ux * uy;
    geomY[tid][4] = uy * uz;
    geomY[tid][5] = (3.f * uz * uz - 1.f) * 0.28867513459481287f;
    geomY[tid][6] = ux * uz;
    geomY[tid][7] = (ux * ux - uy * uy) * 0.5f;
    #pragma unroll
    for (int k = 0; k < 8; ++k) {
      float t = dd - (float)k * (5.0f / 7.0f);
      bufB[576 + tid * 8 + k] = __expf(-t * t);   // rbf
    }
  }
  __syncthreads();

  const int q = lane >> 4, colA = lane & 15;
  const int myrow0 = wid * 16;

  // --- h (scaled by 0.25 = 1/sqrt(AVG_DEG)) into A-fragments (b128 LDS reads) ---
  short8 afrag0, afrag1;
  {
    const float* rb = &bufB[576 + (myrow0 + colA) * 8];
    float rbv[8];
    #pragma unroll
    for (int r = 0; r < 8; ++r) rbv[r] = rb[r];
    float a0[8], a1[8];
    {
      float4v b0 = *(const float4v*)&bufB[512 + q * 8];
      float4v b1 = *(const float4v*)&bufB[512 + q * 8 + 4];
      float4v b2 = *(const float4v*)&bufB[512 + 32 + q * 8];
      float4v b3 = *(const float4v*)&bufB[512 + 32 + q * 8 + 4];
      #pragma unroll
      for (int i = 0; i < 4; ++i) {
        a0[i] = b0[i]; a0[4 + i] = b1[i];
        a1[i] = b2[i]; a1[4 + i] = b3[i];
      }
    }
    #pragma unroll
    for (int r = 0; r < 8; ++r) {
      float4v wA = *(const float4v*)&bufB[r * 64 + q * 8];
      float4v wB = *(const float4v*)&bufB[r * 64 + q * 8 + 4];
      float4v wC = *(const float4v*)&bufB[r * 64 + 32 + q * 8];
      float4v wD = *(const float4v*)&bufB[r * 64 + 32 + q * 8 + 4];
      float rv = rbv[r];
      #pragma unroll
      for (int i = 0; i < 4; ++i) {
        a0[i]     += rv * wA[i];
        a0[4 + i] += rv * wB[i];
        a1[i]     += rv * wC[i];
        a1[4 + i] += rv * wD[i];
      }
    }
    #pragma unroll
    for (int i = 0; i < 8; ++i) {
      float a = a0[i];
      afrag0[i] = (short)f2b(0.25f * a / (1.f + __expf(-a)));
      float a2 = a1[i];
      afrag1[i] = (short)f2b(0.25f * a2 / (1.f + __expf(-a2)));
    }
  }

  // --- 28 MFMA: w for all 16 edges of this wave ---
  float4v acc[14];
  #pragma unroll
  for (int t = 0; t < 14; ++t) {
    int j = t * 16 + colA;
    short8 b0 = *(const short8*)&bufA[j * 72 + q * 8];
    short8 b1 = *(const short8*)&bufA[j * 72 + 32 + q * 8];
    float4v c = {0.f, 0.f, 0.f, 0.f};
    c = __builtin_amdgcn_mfma_f32_16x16x32_bf16(afrag0, b0, c, 0, 0, 0);
    c = __builtin_amdgcn_mfma_f32_16x16x32_bf16(afrag1, b1, c, 0, 0, 0);
    acc[t] = c;
  }

  __syncthreads();   // all waves done reading wr2t; bufA becomes wall

  // --- unload w ONCE per wave: wall[wid][j][18] bf16, el = q*4+r ---
  // acc[t][r] = w[edge q*4+r][j = t*16+colA]
  unsigned short* WL = bufA + wid * 4032;
  #pragma unroll
  for (int t = 0; t < 14; ++t) {
    int j = t * 16 + colA;
    #pragma unroll
    for (int r = 0; r < 4; ++r)
      WL[j * 18 + q * 4 + r] = f2b(acc[t][r]);
  }
  asm volatile("" ::: "memory");

  // --- phase B: half-wave h owns edges myrow0+8h..+8h+7; lane m owns mult m ---
  const int h = lane >> 5, m = lane & 31;
  const int o0 = m, o1 = 32 + 3 * m, o2 = 128 + 5 * m;
  const int el0 = myrow0 + 8 * h;       // first edge of my half

  float accv[9];
  #pragma unroll
  for (int r = 0; r < 9; ++r) accv[r] = 0.f;
  unsigned cur_d = sdv[1][el0];

  // prefetch edge el0's row slice
  unsigned short p0, p1a, p1b, p1c, p2a, p2b, p2c, p2d, p2e;
  {
    const unsigned short* Xp = si1 + (size_t)sdv[0][el0] * DIMX;
    p0 = Xp[o0];
    p1a = Xp[o1]; p1b = Xp[o1 + 1]; p1c = Xp[o1 + 2];
    p2a = Xp[o2]; p2b = Xp[o2 + 1]; p2c = Xp[o2 + 2]; p2d = Xp[o2 + 3]; p2e = Xp[o2 + 4];
  }

  #pragma unroll
  for (int i = 0; i < 8; ++i) {
    // capture current edge values
    float x0v = b2f(p0);
    float x1a = b2f(p1a), x1b = b2f(p1b), x1c = b2f(p1c);
    float x2a = b2f(p2a), x2b = b2f(p2b), x2c = b2f(p2c), x2d = b2f(p2d), x2e = b2f(p2e);
    // prefetch next edge
    if (i < 7) {
      const unsigned short* Xn = si1 + (size_t)sdv[0][el0 + i + 1] * DIMX;
      p0 = Xn[o0];
      p1a = Xn[o1]; p1b = Xn[o1 + 1]; p1c = Xn[o1 + 2];
      p2a = Xn[o2]; p2b = Xn[o2 + 1]; p2c = Xn[o2 + 2]; p2d = Xn[o2 + 3]; p2e = Xn[o2 + 4];
    }
    const int eb = el0 + i;
    const int elc = 8 * h + i;          // 0..15 within wave
    // w reads (7 u16, stride-9-word: conflict-free)
    float w0 = b2f(WL[(0 * 32 + m) * 18 + elc]);
    float w1 = b2f(WL[(1 * 32 + m) * 18 + elc]);
    float w2 = b2f(WL[(2 * 32 + m) * 18 + elc]);
    float w3 = b2f(WL[(3 * 32 + m) * 18 + elc]);
    float w4 = b2f(WL[(4 * 32 + m) * 18 + elc]);
    float w5 = b2f(WL[(5 * 32 + m) * 18 + elc]);
    float w6 = b2f(WL[(6 * 32 + m) * 18 + elc]);
    // Y (broadcast within half)
    float4v g0 = *(const float4v*)&geomY[eb][0];
    float4v g1 = *(const float4v*)&geomY[eb][4];
    float y1x = g0[0], y1y = g0[1], y1z = g0[2], y20 = g0[3];
    float y21 = g1[0], y22 = g1[1], y23 = g1[2], y24 = g1[3];
    // run boundary flush (uniform per half; predicated)
    unsigned dn = sdv[1][eb];
    if (dn != cur_d) {
      float* cv = conv + (size_t)cur_d * DIMX;
      atomicAdd(cv + o0, accv[0]);
      atomicAdd(cv + o1, accv[1]); atomicAdd(cv + o1 + 1, accv[2]); atomicAdd(cv + o1 + 2, accv[3]);
      atomicAdd(cv + o2, accv[4]); atomicAdd(cv + o2 + 1, accv[5]); atomicAdd(cv + o2 + 2, accv[6]);
      atomicAdd(cv + o2 + 3, accv[7]); atomicAdd(cv + o2 + 4, accv[8]);
      #pragma unroll
      for (int r = 0; r < 9; ++r) accv[r] = 0.f;
      cur_d = dn;
    }
    // messages
    float d1 = x1a * y1x + x1b * y1y + x1c * y1z;
    float d2 = x2a * y20 + x2b * y21 + x2c * y22 + x2d * y23 + x2e * y24;
    float w3x0 = w3 * x0v, w5x0 = w5 * x0v;
    accv[0] += w0 * x0v + w4 * d1 + w6 * d2;
    accv[1] += w1 * x1a + w3x0 * y1x;
    accv[2] += w1 * x1b + w3x0 * y1y;
    accv[3] += w1 * x1c + w3x0 * y1z;
    accv[4] += w2 * x2a + w5x0 * y20;
    accv[5] += w2 * x2b + w5x0 * y21;
    accv[6] += w2 * x2c + w5x0 * y22;
    accv[7] += w2 * x2d + w5x0 * y23;
    accv[8] += w2 * x2e + w5x0 * y24;
  }
  // final flush
  {
    float* cv = conv + (size_t)cur_d * DIMX;
    atomicAdd(cv + o0, accv[0]);
    atomicAdd(cv + o1, accv[1]); atomicAdd(cv + o1 + 1, accv[2]); atomicAdd(cv + o1 + 2, accv[3]);
    atomicAdd(cv + o2, accv[4]); atomicAdd(cv + o2 + 1, accv[5]); atomicAdd(cv + o2 + 2, accv[6]);
    atomicAdd(cv + o2 + 3, accv[7]); atomicAdd(cv + o2 + 4, accv[8]);
  }
}

// ---------------- Kernel 4: si2 = linear(conv); mixed = nodes + si2; gate -> fp32 ----------------
__global__ __launch_bounds__(256) void k_gate(
    const float* __restrict__ conv,
    const void* __restrict__ nodes,
    const void* __restrict__ W0,
    const void* __restrict__ W1,
    const void* __restrict__ W2,
    const void* __restrict__ Wg,
    float* __restrict__ out,
    const int* __restrict__ flags) {
  const int f32 = flags[0];
  __shared__ float Ws[3072];
  __shared__ float Wgs[2048];
  __shared__ float xs[NPB * DIMX];
  __shared__ float m0s[NPB][33];
  __shared__ float gs[NPB][65];
  int tid = threadIdx.x;
  for (int idx = tid; idx < 3072; idx += 256) {
    int l = idx >> 10, rem = idx & 1023;
    const void* w = (l == 0) ? W0 : ((l == 1) ? W1 : W2);
    Ws[idx] = ldf(w, rem, f32);
  }
  for (int idx = tid; idx < 2048; idx += 256) Wgs[idx] = ldf(Wg, idx, f32);
  long base = (long)blockIdx.x * NPB;
  for (int idx = tid; idx < NPB * DIMX; idx += 256) xs[idx] = conv[base * DIMX + idx];
  __syncthreads();
  int wid = tid >> 6, lane = tid & 63;
  #pragma unroll 1
  for (int t = 0; t < 4; ++t) {
    int nl = wid * 4 + t;
    long node = base + nl;
    const float* x = xs + nl * DIMX;
    float mixed[5];
    #pragma unroll
    for (int r = 0; r < 5; ++r) {
      int j = r * 64 + lane;
      if (j < DIMX) {
        float acc = 0.f;
        if (j < 32) {
          #pragma unroll
          for (int i = 0; i < 32; ++i) acc += x[i] * Ws[i * 32 + j];
        } else if (j < 128) {
          unsigned jj = j - 32; int m = jj / 3u, c = jj % 3u;
          #pragma unroll
          for (int i = 0; i < 32; ++i) acc += x[32 + 3 * i + c] * Ws[1024 + i * 32 + m];
        } else {
          unsigned jj = j - 128; int m = jj / 5u, c = jj % 5u;
          #pragma unroll
          for (int i = 0; i < 32; ++i) acc += x[128 + 5 * i + c] * Ws[2048 + i * 32 + m];
        }
        acc += ldf(nodes, node * DIMX + j, f32);
        mixed[r] = acc;
        if (j < 32) m0s[nl][j] = acc;
      }
    }
    asm volatile("" ::: "memory");
    {
      float ga = 0.f;
      #pragma unroll
      for (int m = 0; m < 32; ++m) ga += m0s[nl][m] * Wgs[m * 64 + lane];
      gs[nl][lane] = 1.f / (1.f + __expf(-ga));
    }
    asm volatile("" ::: "memory");
    #pragma unroll
    for (int r = 0; r < 5; ++r) {
      int j = r * 64 + lane;
      if (j < DIMX) {
        float v = mixed[r];
        float o;
        if (j < 32) {
          o = v / (1.f + __expf(-v));
        } else if (j < 128) {
          int m = (unsigned)(j - 32) / 3u; o = v * gs[nl][m];
        } else {
          int m = (unsigned)(j - 128) / 5u; o = v * gs[nl][32 + m];
        }
        out[node * DIMX + j] = o;
      }
    }
  }
}

extern "C" void kernel_launch(void* const* d_in, const int* in_sizes, int n_in,
                              void* d_out, int out_size, void* d_ws, size_t ws_size,
                              hipStream_t stream) {
  const void* nodes = d_in[0];
  const void* pos   = d_in[1];
  const void* W0    = d_in[2];
  const void* W1    = d_in[3];
  const void* W2    = d_in[4];
  const void* Wr1   = d_in[5];
  const void* br1   = d_in[6];
  const void* Wr2   = d_in[7];
  const void* Wg    = d_in[8];
  const int* eidx   = (const int*)d_in[10];

  // workspace layout
  int* flags = (int*)d_ws;
  unsigned short* si1 = (unsigned short*)((char*)d_ws + 256);
  size_t conv_off = 256 + (size_t)NN * DIMX * 2;                 // 28,800,256
  float* conv = (float*)((char*)d_ws + conv_off);
  size_t cnt_off = conv_off + (size_t)NN * DIMX * 4;             // 86,400,256
  int* cnt    = (int*)((char*)d_ws + cnt_off);
  int* cursor = (int*)((char*)d_ws + cnt_off + (size_t)NN * 4);  // 86,600,256
  unsigned long long* sedge =
      (unsigned long long*)((char*)d_ws + cnt_off + 2 * (size_t)NN * 4);  // 86,800,256
  float* out = (float*)d_out;

  hipLaunchKernelGGL(k_detect, dim3(1), dim3(64), 0, stream,
                     (const unsigned short*)pos, eidx, flags);
  // counting sort of edges by dst
  hipLaunchKernelGGL(k_zero_cnt, dim3((NN + 255) / 256), dim3(256), 0, stream, cnt);
  hipLaunchKernelGGL(k_hist, dim3((NE + 255) / 256), dim3(256), 0, stream, eidx, cnt, flags);
  hipLaunchKernelGGL(k_scan, dim3(1), dim3(1024), 0, stream, cnt, cursor);
  hipLaunchKernelGGL(k_scatter, dim3((NE + 255) / 256), dim3(256), 0, stream,
                     eidx, cursor, sedge, flags);
  // node pipeline
  hipLaunchKernelGGL(k_linear1, dim3(NN / NPB), dim3(256), 0, stream,
                     nodes, W0, W1, W2, si1, flags);
  hipLaunchKernelGGL(k_zero, dim3((NN * DIMX / 4 + 255) / 256), dim3(256), 0, stream, conv);
  hipLaunchKernelGGL(k_edges, dim3(NE / 64), dim3(256), 0, stream,
                     pos, sedge, Wr1, br1, Wr2, si1, conv, flags);
  hipLaunchKernelGGL(k_gate, dim3(NN / NPB), dim3(256), 0, stream,
                     conv, nodes, W0, W1, W2, Wg, out, flags);
}

// Round 6
// 1190.848 us; speedup vs baseline: 1.0201x; 1.0128x over previous
//
#include <hip/hip_runtime.h>
#include <hip/hip_bf16.h>

#define NN 50000
#define NE 800000
#define DIMX 288
#define NPB 16   // nodes per block in k_linear1 / k_gate

typedef float float4v __attribute__((ext_vector_type(4)));
typedef short short8 __attribute__((ext_vector_type(8)));

__device__ __forceinline__ float b2f(unsigned short u) {
  return __uint_as_float(((unsigned int)u) << 16);
}
__device__ __forceinline__ float b2f_lo(unsigned int u) {
  return __uint_as_float(u << 16);
}
__device__ __forceinline__ float b2f_hi(unsigned int u) {
  return __uint_as_float(u & 0xffff0000u);
}
__device__ __forceinline__ unsigned short f2b(float f) {
  unsigned int x = __float_as_uint(f);
  x += 0x7fffu + ((x >> 16) & 1u);
  return (unsigned short)(x >> 16);
}
__device__ __forceinline__ float ldf(const void* p, long i, int f32) {
  return f32 ? ((const float*)p)[i] : b2f(((const unsigned short*)p)[i]);
}
__device__ __forceinline__ int ldidx(const int* p, long i, int i64) {
  return i64 ? p[2 * i] : p[i];
}

// ---------------- Kernel 0: dtype detector ----------------
__global__ void k_detect(const unsigned short* __restrict__ pos_u16,
                         const int* __restrict__ eidx_i32,
                         int* __restrict__ flags) {
  if (threadIdx.x == 0 && blockIdx.x == 0) {
    int insane = 0;
    for (int i = 0; i < 128; ++i) {
      unsigned short u = pos_u16[i];
      int e = (u >> 7) & 0xff;
      if (e >= 0xC2) insane++;          // |x| >= 2^67 impossible for bf16 pos in [0,10]
    }
    flags[0] = (insane >= 2) ? 1 : 0;
    int nz = 0;
    for (int i = 1; i < 16; i += 2) nz += (eidx_i32[i] != 0);
    flags[1] = (nz == 0) ? 1 : 0;       // int64 high words all zero
  }
}

// ---------------- Counting sort by dst: zero-cnt, hist, scan, scatter ----------------
__global__ __launch_bounds__(256) void k_zero_cnt(int* __restrict__ cnt) {
  int i = blockIdx.x * 256 + threadIdx.x;
  if (i < NN) cnt[i] = 0;
}

__global__ __launch_bounds__(256) void k_hist(const int* __restrict__ eidx,
                                              int* __restrict__ cnt,
                                              const int* __restrict__ flags) {
  const int i64 = flags[1];
  long e = (long)blockIdx.x * 256 + threadIdx.x;
  if (e < NE) {
    int d = ldidx(eidx, NE + e, i64);
    atomicAdd(&cnt[d], 1);
  }
}

// single block, 1024 threads: exclusive prefix sum of cnt -> cursor
__global__ __launch_bounds__(1024) void k_scan(const int* __restrict__ cnt,
                                               int* __restrict__ cursor) {
  __shared__ int part[1024];
  int t = threadIdx.x;
  const int CH = (NN + 1023) / 1024;   // 49
  int lo = t * CH, hi = lo + CH; if (hi > NN) hi = NN;
  int s = 0;
  for (int i = lo; i < hi; ++i) s += cnt[i];
  part[t] = s;
  __syncthreads();
  for (int off = 1; off < 1024; off <<= 1) {
    int v = (t >= off) ? part[t - off] : 0;
    __syncthreads();
    part[t] += v;
    __syncthreads();
  }
  int run = (t > 0) ? part[t - 1] : 0;
  for (int i = lo; i < hi; ++i) { int c = cnt[i]; cursor[i] = run; run += c; }
}

__global__ __launch_bounds__(256) void k_scatter(const int* __restrict__ eidx,
                                                 int* __restrict__ cursor,
                                                 unsigned long long* __restrict__ sedge,
                                                 const int* __restrict__ flags) {
  const int i64 = flags[1];
  long e = (long)blockIdx.x * 256 + threadIdx.x;
  if (e < NE) {
    int s = ldidx(eidx, e, i64);
    int d = ldidx(eidx, NE + e, i64);
    int p = atomicAdd(&cursor[d], 1);
    sedge[p] = ((unsigned long long)(unsigned)d << 32) | (unsigned)s;
  }
}

// ---------------- Kernel 1: si1 = irreps_linear(nodes) -> bf16 (packed) + zero conv ---
// si1 row layout (288 shorts): for m in 0..31: slots [m*8 .. m*8+7] =
// {x0[m], x1[m][0..2], x2[m][0..3]}; x2[m][4] at [256+m]. This makes each
// lane's phase-B read footprint contiguous: one dwordx4 + one u16.
__global__ __launch_bounds__(256) void k_linear1(
    const void* __restrict__ nodes,
    const void* __restrict__ W0,
    const void* __restrict__ W1,
    const void* __restrict__ W2,
    unsigned short* __restrict__ si1,
    float* __restrict__ conv,
    const int* __restrict__ flags) {
  const int f32 = flags[0];
  __shared__ float Ws[3072];
  __shared__ float xs[NPB * DIMX];
  int tid = threadIdx.x;
  for (int idx = tid; idx < 3072; idx += 256) {
    int l = idx >> 10, rem = idx & 1023;
    const void* w = (l == 0) ? W0 : ((l == 1) ? W1 : W2);
    Ws[idx] = ldf(w, rem, f32);
  }
  long base = (long)blockIdx.x * NPB;
  for (int idx = tid; idx < NPB * DIMX; idx += 256)
    xs[idx] = ldf(nodes, base * DIMX + idx, f32);
  // zero this block's slice of conv (replaces the k_zero kernel)
  {
    float4 z; z.x = 0.f; z.y = 0.f; z.z = 0.f; z.w = 0.f;
    float4* cz = (float4*)(conv + base * DIMX);
    for (int idx = tid; idx < NPB * DIMX / 4; idx += 256) cz[idx] = z;
  }
  __syncthreads();
  int wid = tid >> 6, lane = tid & 63;
  #pragma unroll 1
  for (int t = 0; t < 4; ++t) {
    int nl = wid * 4 + t;
    long node = base + nl;
    const float* x = xs + nl * DIMX;
    #pragma unroll
    for (int r = 0; r < 5; ++r) {
      int j = r * 64 + lane;
      if (j < DIMX) {
        float acc = 0.f;
        int slot;
        if (j < 32) {
          #pragma unroll
          for (int i = 0; i < 32; ++i) acc += x[i] * Ws[i * 32 + j];
          slot = j * 8;
        } else if (j < 128) {
          unsigned jj = j - 32; int m = jj / 3u, c = jj % 3u;
          #pragma unroll
          for (int i = 0; i < 32; ++i) acc += x[32 + 3 * i + c] * Ws[1024 + i * 32 + m];
          slot = m * 8 + 1 + c;
        } else {
          unsigned jj = j - 128; int m = jj / 5u, c = jj % 5u;
          #pragma unroll
          for (int i = 0; i < 32; ++i) acc += x[128 + 5 * i + c] * Ws[2048 + i * 32 + m];
          slot = (c < 4) ? (m * 8 + 4 + c) : (256 + m);
        }
        si1[node * DIMX + slot] = f2b(acc);
      }
    }
  }
}

// ---------------- Kernel 3: fused edge kernel (dst-sorted edges) ----------------
// Phase B: lane<->m mapping; half-wave h owns 8 contiguous edges. Per edge:
// ONE dwordx4 + ONE u16 global load (packed si1 row), 2-deep prefetch;
// 7 LDS u16 w-reads (wall, stride-9-word conflict-free); 2 b128 Y reads;
// run-accumulate in VGPRs, scattered atomics at run boundaries.
__global__ __launch_bounds__(256) void k_edges(
    const void* __restrict__ pos,
    const unsigned long long* __restrict__ sedge,
    const void* __restrict__ Wr1,
    const void* __restrict__ br1,
    const void* __restrict__ Wr2,
    const unsigned short* __restrict__ si1,
    float* __restrict__ conv,
    const int* __restrict__ flags) {
  const int f32 = flags[0];
  // bufA: phase A = wr2t[j*72+k] (16128 shorts); phase B = wall[4 waves][224][18] bf16
  __shared__ __align__(16) unsigned short bufA[16128];
  // bufB: phase A only = wr1s[512]+br1[64] @0, rbf[64][8] @576
  __shared__ __align__(16) float bufB[1088];
  __shared__ __align__(16) float geomY[64][8];  // Y1(3) Y2(5), live whole kernel
  __shared__ unsigned int sdv[2][64];           // src, dst
  int tid = threadIdx.x, lane = tid & 63, wid = tid >> 6;

  for (int idx = tid; idx < 512; idx += 256) bufB[idx] = ldf(Wr1, idx, f32);
  if (tid < 64) bufB[512 + tid] = ldf(br1, tid, f32);
  for (int idx = tid; idx < 64 * 224; idx += 256) {   // global-coalesced, transpose into LDS
    int k = idx / 224, j = idx - k * 224;
    bufA[j * 72 + k] = f2b(ldf(Wr2, idx, f32));
  }
  if (tid < 64) {
    long e = (long)blockIdx.x * 64 + tid;
    unsigned long long pr = sedge[e];
    int s = (int)(pr & 0xffffffffu);
    int d = (int)(pr >> 32);
    sdv[0][tid] = (unsigned)s; sdv[1][tid] = (unsigned)d;
    float rx = ldf(pos, 3 * (long)s, f32)     - ldf(pos, 3 * (long)d, f32);
    float ry = ldf(pos, 3 * (long)s + 1, f32) - ldf(pos, 3 * (long)d + 1, f32);
    float rz = ldf(pos, 3 * (long)s + 2, f32) - ldf(pos, 3 * (long)d + 2, f32);
    float dd = sqrtf(rx * rx + ry * ry + rz * rz + 1e-12f);
    float inv = 1.0f / dd;
    float ux = rx * inv, uy = ry * inv, uz = rz * inv;
    geomY[tid][0] = ux; geomY[tid][1] = uy; geomY[tid][2] = uz;
    geomY[tid][3] = ux * uy;
    geomY[tid][4] = uy * uz;
    geomY[tid][5] = (3.f * uz * uz - 1.f) * 0.28867513459481287f;
    geomY[tid][6] = ux * uz;
    geomY[tid][7] = (ux * ux - uy * uy) * 0.5f;
    #pragma unroll
    for (int k = 0; k < 8; ++k) {
      float t = dd - (float)k * (5.0f / 7.0f);
      bufB[576 + tid * 8 + k] = __expf(-t * t);   // rbf
    }
  }
  __syncthreads();

  const int q = lane >> 4, colA = lane & 15;
  const int myrow0 = wid * 16;

  // --- h (scaled by 0.25 = 1/sqrt(AVG_DEG)) into A-fragments (b128 LDS reads) ---
  short8 afrag0, afrag1;
  {
    const float* rb = &bufB[576 + (myrow0 + colA) * 8];
    float rbv[8];
    #pragma unroll
    for (int r = 0; r < 8; ++r) rbv[r] = rb[r];
    float a0[8], a1[8];
    {
      float4v b0 = *(const float4v*)&bufB[512 + q * 8];
      float4v b1 = *(const float4v*)&bufB[512 + q * 8 + 4];
      float4v b2 = *(const float4v*)&bufB[512 + 32 + q * 8];
      float4v b3 = *(const float4v*)&bufB[512 + 32 + q * 8 + 4];
      #pragma unroll
      for (int i = 0; i < 4; ++i) {
        a0[i] = b0[i]; a0[4 + i] = b1[i];
        a1[i] = b2[i]; a1[4 + i] = b3[i];
      }
    }
    #pragma unroll
    for (int r = 0; r < 8; ++r) {
      float4v wA = *(const float4v*)&bufB[r * 64 + q * 8];
      float4v wB = *(const float4v*)&bufB[r * 64 + q * 8 + 4];
      float4v wC = *(const float4v*)&bufB[r * 64 + 32 + q * 8];
      float4v wD = *(const float4v*)&bufB[r * 64 + 32 + q * 8 + 4];
      float rv = rbv[r];
      #pragma unroll
      for (int i = 0; i < 4; ++i) {
        a0[i]     += rv * wA[i];
        a0[4 + i] += rv * wB[i];
        a1[i]     += rv * wC[i];
        a1[4 + i] += rv * wD[i];
      }
    }
    #pragma unroll
    for (int i = 0; i < 8; ++i) {
      float a = a0[i];
      afrag0[i] = (short)f2b(0.25f * a / (1.f + __expf(-a)));
      float a2 = a1[i];
      afrag1[i] = (short)f2b(0.25f * a2 / (1.f + __expf(-a2)));
    }
  }

  // --- 28 MFMA: w for all 16 edges of this wave ---
  float4v acc[14];
  #pragma unroll
  for (int t = 0; t < 14; ++t) {
    int j = t * 16 + colA;
    short8 b0 = *(const short8*)&bufA[j * 72 + q * 8];
    short8 b1 = *(const short8*)&bufA[j * 72 + 32 + q * 8];
    float4v c = {0.f, 0.f, 0.f, 0.f};
    c = __builtin_amdgcn_mfma_f32_16x16x32_bf16(afrag0, b0, c, 0, 0, 0);
    c = __builtin_amdgcn_mfma_f32_16x16x32_bf16(afrag1, b1, c, 0, 0, 0);
    acc[t] = c;
  }

  __syncthreads();   // all waves done reading wr2t; bufA becomes wall

  // --- unload w ONCE per wave: wall[wid][j][18] bf16, el = q*4+r ---
  unsigned short* WL = bufA + wid * 4032;
  #pragma unroll
  for (int t = 0; t < 14; ++t) {
    int j = t * 16 + colA;
    #pragma unroll
    for (int r = 0; r < 4; ++r)
      WL[j * 18 + q * 4 + r] = f2b(acc[t][r]);
  }
  asm volatile("" ::: "memory");

  // --- phase B: half-wave h owns edges myrow0+8h..+8h+7; lane m owns mult m ---
  const int h = lane >> 5, m = lane & 31;
  const int o0 = m, o1 = 32 + 3 * m, o2 = 128 + 5 * m;
  const int el0 = myrow0 + 8 * h;       // first edge of my half

  float accv[9];
  #pragma unroll
  for (int r = 0; r < 9; ++r) accv[r] = 0.f;
  unsigned cur_d = sdv[1][el0];

  // 2-deep prefetch of packed row slices (dwordx4 + u16 per edge)
  uint4 A0, A1; unsigned short E0, E1;
  {
    const char* r0 = (const char*)si1 + (size_t)sdv[0][el0] * 576;
    A0 = *(const uint4*)(r0 + m * 16);
    E0 = *(const unsigned short*)(r0 + 512 + 2 * m);
    const char* r1 = (const char*)si1 + (size_t)sdv[0][el0 + 1] * 576;
    A1 = *(const uint4*)(r1 + m * 16);
    E1 = *(const unsigned short*)(r1 + 512 + 2 * m);
  }

  #pragma unroll
  for (int i = 0; i < 8; ++i) {
    uint4 cur; unsigned short ce;
    if ((i & 1) == 0) { cur = A0; ce = E0; } else { cur = A1; ce = E1; }
    // issue prefetch for edge i+2 into the slot just consumed
    if (i < 6) {
      const char* rn = (const char*)si1 + (size_t)sdv[0][el0 + i + 2] * 576;
      if ((i & 1) == 0) {
        A0 = *(const uint4*)(rn + m * 16);
        E0 = *(const unsigned short*)(rn + 512 + 2 * m);
      } else {
        A1 = *(const uint4*)(rn + m * 16);
        E1 = *(const unsigned short*)(rn + 512 + 2 * m);
      }
    }
    // unpack current edge values (slots: x0,x1a,x1b,x1c,x2a,x2b,x2c,x2d | x2e)
    float x0v = b2f_lo(cur.x), x1a = b2f_hi(cur.x);
    float x1b = b2f_lo(cur.y), x1c = b2f_hi(cur.y);
    float x2a = b2f_lo(cur.z), x2b = b2f_hi(cur.z);
    float x2c = b2f_lo(cur.w), x2d = b2f_hi(cur.w);
    float x2e = b2f(ce);

    const int eb = el0 + i;
    const int elc = 8 * h + i;          // 0..15 within wave
    // w reads (7 u16, stride-9-word: conflict-free)
    float w0 = b2f(WL[(0 * 32 + m) * 18 + elc]);
    float w1 = b2f(WL[(1 * 32 + m) * 18 + elc]);
    float w2 = b2f(WL[(2 * 32 + m) * 18 + elc]);
    float w3 = b2f(WL[(3 * 32 + m) * 18 + elc]);
    float w4 = b2f(WL[(4 * 32 + m) * 18 + elc]);
    float w5 = b2f(WL[(5 * 32 + m) * 18 + elc]);
    float w6 = b2f(WL[(6 * 32 + m) * 18 + elc]);
    // Y (broadcast within half)
    float4v g0 = *(const float4v*)&geomY[eb][0];
    float4v g1 = *(const float4v*)&geomY[eb][4];
    float y1x = g0[0], y1y = g0[1], y1z = g0[2], y20 = g0[3];
    float y21 = g1[0], y22 = g1[1], y23 = g1[2], y24 = g1[3];
    // run boundary flush (uniform per half; predicated)
    unsigned dn = sdv[1][eb];
    if (dn != cur_d) {
      float* cv = conv + (size_t)cur_d * DIMX;
      atomicAdd(cv + o0, accv[0]);
      atomicAdd(cv + o1, accv[1]); atomicAdd(cv + o1 + 1, accv[2]); atomicAdd(cv + o1 + 2, accv[3]);
      atomicAdd(cv + o2, accv[4]); atomicAdd(cv + o2 + 1, accv[5]); atomicAdd(cv + o2 + 2, accv[6]);
      atomicAdd(cv + o2 + 3, accv[7]); atomicAdd(cv + o2 + 4, accv[8]);
      #pragma unroll
      for (int r = 0; r < 9; ++r) accv[r] = 0.f;
      cur_d = dn;
    }
    // messages
    float d1 = x1a * y1x + x1b * y1y + x1c * y1z;
    float d2 = x2a * y20 + x2b * y21 + x2c * y22 + x2d * y23 + x2e * y24;
    float w3x0 = w3 * x0v, w5x0 = w5 * x0v;
    accv[0] += w0 * x0v + w4 * d1 + w6 * d2;
    accv[1] += w1 * x1a + w3x0 * y1x;
    accv[2] += w1 * x1b + w3x0 * y1y;
    accv[3] += w1 * x1c + w3x0 * y1z;
    accv[4] += w2 * x2a + w5x0 * y20;
    accv[5] += w2 * x2b + w5x0 * y21;
    accv[6] += w2 * x2c + w5x0 * y22;
    accv[7] += w2 * x2d + w5x0 * y23;
    accv[8] += w2 * x2e + w5x0 * y24;
  }
  // final flush
  {
    float* cv = conv + (size_t)cur_d * DIMX;
    atomicAdd(cv + o0, accv[0]);
    atomicAdd(cv + o1, accv[1]); atomicAdd(cv + o1 + 1, accv[2]); atomicAdd(cv + o1 + 2, accv[3]);
    atomicAdd(cv + o2, accv[4]); atomicAdd(cv + o2 + 1, accv[5]); atomicAdd(cv + o2 + 2, accv[6]);
    atomicAdd(cv + o2 + 3, accv[7]); atomicAdd(cv + o2 + 4, accv[8]);
  }
}

// ---------------- Kernel 4: si2 = linear(conv); mixed = nodes + si2; gate -> fp32 ----------------
__global__ __launch_bounds__(256) void k_gate(
    const float* __restrict__ conv,
    const void* __restrict__ nodes,
    const void* __restrict__ W0,
    const void* __restrict__ W1,
    const void* __restrict__ W2,
    const void* __restrict__ Wg,
    float* __restrict__ out,
    const int* __restrict__ flags) {
  const int f32 = flags[0];
  __shared__ float Ws[3072];
  __shared__ float Wgs[2048];
  __shared__ float xs[NPB * DIMX];
  __shared__ float m0s[NPB][33];
  __shared__ float gs[NPB][65];
  int tid = threadIdx.x;
  for (int idx = tid; idx < 3072; idx += 256) {
    int l = idx >> 10, rem = idx & 1023;
    const void* w = (l == 0) ? W0 : ((l == 1) ? W1 : W2);
    Ws[idx] = ldf(w, rem, f32);
  }
  for (int idx = tid; idx < 2048; idx += 256) Wgs[idx] = ldf(Wg, idx, f32);
  long base = (long)blockIdx.x * NPB;
  for (int idx = tid; idx < NPB * DIMX; idx += 256) xs[idx] = conv[base * DIMX + idx];
  __syncthreads();
  int wid = tid >> 6, lane = tid & 63;
  #pragma unroll 1
  for (int t = 0; t < 4; ++t) {
    int nl = wid * 4 + t;
    long node = base + nl;
    const float* x = xs + nl * DIMX;
    float mixed[5];
    #pragma unroll
    for (int r = 0; r < 5; ++r) {
      int j = r * 64 + lane;
      if (j < DIMX) {
        float acc = 0.f;
        if (j < 32) {
          #pragma unroll
          for (int i = 0; i < 32; ++i) acc += x[i] * Ws[i * 32 + j];
        } else if (j < 128) {
          unsigned jj = j - 32; int m = jj / 3u, c = jj % 3u;
          #pragma unroll
          for (int i = 0; i < 32; ++i) acc += x[32 + 3 * i + c] * Ws[1024 + i * 32 + m];
        } else {
          unsigned jj = j - 128; int m = jj / 5u, c = jj % 5u;
          #pragma unroll
          for (int i = 0; i < 32; ++i) acc += x[128 + 5 * i + c] * Ws[2048 + i * 32 + m];
        }
        acc += ldf(nodes, node * DIMX + j, f32);
        mixed[r] = acc;
        if (j < 32) m0s[nl][j] = acc;
      }
    }
    asm volatile("" ::: "memory");
    {
      float ga = 0.f;
      #pragma unroll
      for (int m = 0; m < 32; ++m) ga += m0s[nl][m] * Wgs[m * 64 + lane];
      gs[nl][lane] = 1.f / (1.f + __expf(-ga));
    }
    asm volatile("" ::: "memory");
    #pragma unroll
    for (int r = 0; r < 5; ++r) {
      int j = r * 64 + lane;
      if (j < DIMX) {
        float v = mixed[r];
        float o;
        if (j < 32) {
          o = v / (1.f + __expf(-v));
        } else if (j < 128) {
          int m = (unsigned)(j - 32) / 3u; o = v * gs[nl][m];
        } else {
          int m = (unsigned)(j - 128) / 5u; o = v * gs[nl][32 + m];
        }
        out[node * DIMX + j] = o;
      }
    }
  }
}

extern "C" void kernel_launch(void* const* d_in, const int* in_sizes, int n_in,
                              void* d_out, int out_size, void* d_ws, size_t ws_size,
                              hipStream_t stream) {
  const void* nodes = d_in[0];
  const void* pos   = d_in[1];
  const void* W0    = d_in[2];
  const void* W1    = d_in[3];
  const void* W2    = d_in[4];
  const void* Wr1   = d_in[5];
  const void* br1   = d_in[6];
  const void* Wr2   = d_in[7];
  const void* Wg    = d_in[8];
  const int* eidx   = (const int*)d_in[10];

  // workspace layout
  int* flags = (int*)d_ws;
  unsigned short* si1 = (unsigned short*)((char*)d_ws + 256);
  size_t conv_off = 256 + (size_t)NN * DIMX * 2;                 // 28,800,256
  float* conv = (float*)((char*)d_ws + conv_off);
  size_t cnt_off = conv_off + (size_t)NN * DIMX * 4;             // 86,400,256
  int* cnt    = (int*)((char*)d_ws + cnt_off);
  int* cursor = (int*)((char*)d_ws + cnt_off + (size_t)NN * 4);  // 86,600,256
  unsigned long long* sedge =
      (unsigned long long*)((char*)d_ws + cnt_off + 2 * (size_t)NN * 4);  // 86,800,256
  float* out = (float*)d_out;

  hipLaunchKernelGGL(k_detect, dim3(1), dim3(64), 0, stream,
                     (const unsigned short*)pos, eidx, flags);
  // counting sort of edges by dst
  hipLaunchKernelGGL(k_zero_cnt, dim3((NN + 255) / 256), dim3(256), 0, stream, cnt);
  hipLaunchKernelGGL(k_hist, dim3((NE + 255) / 256), dim3(256), 0, stream, eidx, cnt, flags);
  hipLaunchKernelGGL(k_scan, dim3(1), dim3(1024), 0, stream, cnt, cursor);
  hipLaunchKernelGGL(k_scatter, dim3((NE + 255) / 256), dim3(256), 0, stream,
                     eidx, cursor, sedge, flags);
  // node pipeline (k_linear1 also zeroes conv; k_zero launch removed)
  hipLaunchKernelGGL(k_linear1, dim3(NN / NPB), dim3(256), 0, stream,
                     nodes, W0, W1, W2, si1, conv, flags);
  hipLaunchKernelGGL(k_edges, dim3(NE / 64), dim3(256), 0, stream,
                     pos, sedge, Wr1, br1, Wr2, si1, conv, flags);
  hipLaunchKernelGGL(k_gate, dim3(NN / NPB), dim3(256), 0, stream,
                     conv, nodes, W0, W1, W2, Wg, out, flags);
}